// Round 4
// baseline (77.541 us; speedup 1.0000x reference)
//
#include <hip/hip_runtime.h>
#include <hip/hip_bf16.h>
#include <math.h>

#define N_ 256
#define C_ 100
#define D_ 512
#define ST 368          // Gram stride (23 tiles of 16)
#define NTILE 23
#define NWTILE 529      // 23*23 wave-tiles
#define LOG2E 1.44269504088896f

typedef __attribute__((ext_vector_type(8))) short short8;
typedef __attribute__((ext_vector_type(4))) float floatx4;

__device__ inline float waveReduceSum(float v) {
    #pragma unroll
    for (int off = 32; off > 0; off >>= 1) v += __shfl_xor(v, off, 64);
    return v;
}
__device__ inline float clip1(float x) { return fminf(fmaxf(x, -1.0f), 1.0f); }

__device__ inline short8 cvt8(float4 a, float4 b) {
    union { __hip_bfloat16 h[8]; short8 s; } u;
    u.h[0] = __float2bfloat16(a.x); u.h[1] = __float2bfloat16(a.y);
    u.h[2] = __float2bfloat16(a.z); u.h[3] = __float2bfloat16(a.w);
    u.h[4] = __float2bfloat16(b.x); u.h[5] = __float2bfloat16(b.y);
    u.h[6] = __float2bfloat16(b.z); u.h[7] = __float2bfloat16(b.w);
    return u.s;
}

// K1: Gram = Y Y^T with Y = [X;P] cast to bf16 in-register (validated across
// R1/R6-R10, absmax 0.0). One 16x16 tile/wave via mfma_f32_16x16x32_bf16.
// C/D: col=lane&15, row=quad*4+reg (m89). Rows >= 356 clamp to 0 (garbage,
// finite, never consumed). Diag tiles emit rn[r] = 3*rsqrt(G[r][r]).
// VERBATIM from the best-measured R1 config.
__global__ void gemm_kernel(const float* __restrict__ X,
                            const float* __restrict__ P,
                            float* __restrict__ G,
                            float* __restrict__ rn) {
    int wid = blockIdx.x * 4 + (threadIdx.x >> 6);
    if (wid >= NWTILE) return;
    int lane = threadIdx.x & 63;
    int r = lane & 15, quad = lane >> 4;
    int tm = wid / NTILE, tn = wid - tm * NTILE;
    int ra = tm * 16 + r; if (ra >= 356) ra = 0;
    int rb = tn * 16 + r; if (rb >= 356) rb = 0;
    const float* arow = (ra < N_) ? (X + (size_t)ra * D_) : (P + (size_t)(ra - N_) * D_);
    const float* brow = (rb < N_) ? (X + (size_t)rb * D_) : (P + (size_t)(rb - N_) * D_);
    floatx4 acc = {0.0f, 0.0f, 0.0f, 0.0f};
    #pragma unroll
    for (int kc = 0; kc < D_; kc += 32) {
        const float4* ap = (const float4*)(arow + kc + quad * 8);
        const float4* bp = (const float4*)(brow + kc + quad * 8);
        short8 av = cvt8(ap[0], ap[1]);
        short8 bv = cvt8(bp[0], bp[1]);
        acc = __builtin_amdgcn_mfma_f32_16x16x32_bf16(av, bv, acc, 0, 0, 0);
    }
    int row0 = tm * 16 + quad * 4, col = tn * 16 + r;
    #pragma unroll
    for (int i = 0; i < 4; ++i)
        G[(size_t)(row0 + i) * ST + col] = acc[i];
    if (tm == tn && (r >> 2) == quad) {
        float d = acc[r & 3];                        // Gram[col][col]
        rn[tm * 16 + r] = 3.0f * rsqrtf(fmaxf(d, 1e-24f));
    }
}

// K2 (restructured): 512 blocks x 512 threads = 4096 waves = 4 waves/SIMD,
// 2 blocks/CU (31 KB LDS each). Block (b = blk&255, h = blk>>8) owns pair
// deltas d in [h*64+1, h*64+64] for anchor i1 = b.
//  - Stages its 64 partner proxy-rows of G (raw IPs) into LDS (stride 104
//    floats -> worst 2-way bank conflicts = free), plus the block-uniform
//    anchor row, g-row, scales, T.
//  - Slot = 8 lanes (m = t>>3, q = t&7): one pair per slot, LSE over 100
//    classes in 4 float4 iters/lane (~13 exps), 3-shfl slot reduce.
//  - Diag (real loss) = second iteration of slot 0 at h=0 with lam=1
//    (exact reduction, validated R2/R3); d=128 = h=1 slot 63, masked b<128.
//  - Per-block redundant count via LDS histogram; one atomicAdd per block.
// Math identical to the validated R1 kernel (scales folded into la/lb,
// sp[c] applied per class; clip only feeds lam).
__global__ __launch_bounds__(512)
void pair_kernel(const float* __restrict__ G, const float* __restrict__ rn,
                 const int* __restrict__ T, float* __restrict__ out) {
    __shared__ __attribute__((aligned(16))) float XPl[64 * 104];
    __shared__ __attribute__((aligned(16))) float al[104];
    __shared__ __attribute__((aligned(16))) float sps[104];
    __shared__ float gl[256];
    __shared__ float sxs[256];
    __shared__ int   Tl[256];
    __shared__ int   hist[104];
    __shared__ float red[8];

    int t = threadIdx.x;
    int w = t >> 6, lane = t & 63;
    int bh = blockIdx.x;
    int b = bh & 255, h = bh >> 8;
    int base = h * 64 + 1;               // first d this block handles

    // ---- phase A: zero hist + stage everything ----
    if (t < 104) { hist[t] = 0; sps[t] = (t < C_) ? rn[256 + t] : 0.0f; }
    if (t < 256) { sxs[t] = rn[t]; Tl[t] = T[t]; gl[t] = G[(size_t)b * ST + t]; }
    if (t < C_)  al[t] = G[(size_t)b * ST + 256 + t];
    #pragma unroll
    for (int it = 0; it < 4; ++it) {
        int id = t + 512 * it;           // 1600 float4 chunks: 64 rows x 25
        if (id < 1600) {
            int row = id / 25, c4 = id - row * 25;
            int gr = (b + base + row) & 255;
            *(float4*)&XPl[row * 104 + c4 * 4] =
                *(const float4*)(G + (size_t)gr * ST + 256 + c4 * 4);
        }
    }
    __syncthreads();                     // b1: stage complete
    if (t < 256) atomicAdd(&hist[Tl[t]], 1);

    // ---- phase B: one pair per 8-lane slot ----
    int m = t >> 3, q = t & 7;           // slot in [0,64), class phase
    int t1 = Tl[b];
    float s1 = sxs[b];
    float contrib = 0.0f;
    int nit = (h == 0 && m == 0) ? 2 : 1;
    for (int it = 0; it < nit; ++it) {
        bool isdiag = (it == 1);
        int dd = base + m;               // d in [1,128]
        int i2 = isdiag ? b : ((b + dd) & 255);
        int t2 = Tl[i2];
        // d=128 pair exists only for b<128 (cyclic decomposition, each
        // unordered pair exactly once; formula swap-symmetric, validated R3)
        bool act = isdiag || ((t2 != t1) && (dd < 128 || b < 128));
        if (!act) continue;              // slot-uniform -> shfl partners consistent
        const float* rowB = isdiag ? al : &XPl[m * 104];
        float sc2 = sxs[i2];
        float ip11 = al[t1] * s1 * sps[t1];
        float ip12 = al[t2] * s1 * sps[t2];
        float ip21 = rowB[t1] * sc2 * sps[t1];
        float ip22 = rowB[t2] * sc2 * sps[t2];
        float X1P1 = clip1(ip11), X1P2 = clip1(ip12);
        float X2P1 = clip1(ip21), X2P2 = clip1(ip22);
        float num = X2P2 - X2P1;
        float den = num + X1P1 - X1P2;
        float lam = fminf(fmaxf(num / den, 0.3f), 0.7f);
        if (isdiag) lam = 1.0f;          // exact real-loss reduction
        float oml = 1.0f - lam;
        float g = gl[i2] * s1 * sc2;     // 9*cos(x_b, x_i2); unused when lam=1
        float wn2 = 9.0f * (lam * lam + oml * oml) + 2.0f * lam * oml * g;
        float ss2 = 6.0f * rsqrtf(fmaxf(wn2, 1e-24f));
        float la = ss2 * lam * s1 * LOG2E, lb = ss2 * oml * sc2 * LOG2E;
        float sm = 0.0f;
        #pragma unroll
        for (int k = 0; k < 4; ++k) {
            int c = q * 4 + 32 * k;
            if (c < C_) {
                float4 a1 = *(const float4*)&al[c];
                float4 a2 = *(const float4*)&rowB[c];
                float4 s4 = *(const float4*)&sps[c];
                sm += exp2f(s4.x * (la * a1.x + lb * a2.x));
                sm += exp2f(s4.y * (la * a1.y + lb * a2.y));
                sm += exp2f(s4.z * (la * a1.z + lb * a2.z));
                sm += exp2f(s4.w * (la * a1.w + lb * a2.w));
            }
        }
        sm += __shfl_xor(sm, 1, 64);     // 8-lane slot reduce (partners
        sm += __shfl_xor(sm, 2, 64);     //  stay inside the slot; act is
        sm += __shfl_xor(sm, 4, 64);     //  slot-uniform)
        if (q == 0) {
            float LSE = logf(sm);
            float ec1 = ss2 * (lam * ip11 + oml * ip21);
            float ec2 = ss2 * (lam * ip12 + oml * ip22);
            contrib += LSE - lam * ec1 - oml * ec2;
        }
    }
    float rsum = waveReduceSum(contrib);
    if (lane == 0) red[w] = rsum;
    __syncthreads();                     // b2: red + hist atomics complete

    // ---- epilogue: wave 0 computes count + block partial, one atomic ----
    if (w == 0) {
        float same = 0.0f;
        { float n = (float)hist[lane]; same = 0.5f * n * (n - 1.0f); }
        if (lane + 64 < C_) { float n = (float)hist[lane + 64]; same += 0.5f * n * (n - 1.0f); }
        float bs = (lane < 8) ? red[lane] : 0.0f;
        same = waveReduceSum(same);
        bs = waveReduceSum(bs);
        if (lane == 0) atomicAdd(out, bs / (32896.0f - same));
    }
}

extern "C" void kernel_launch(void* const* d_in, const int* in_sizes, int n_in,
                              void* d_out, int out_size, void* d_ws, size_t ws_size,
                              hipStream_t stream) {
    const float* X = (const float*)d_in[0];   // (256, 512) f32
    const float* P = (const float*)d_in[1];   // (100, 512) f32
    const int*   T = (const int*)d_in[2];     // (256,) i32
    // d_in[3] = indices, unused
    float* ws = (float*)d_ws;
    float* G  = ws;                           // 368*368 = 135424 f32
    float* rn = ws + 135424;                  // 368 f32 (total ~531 KB)
    float* out = (float*)d_out;

    gemm_kernel<<<133, 256, 0, stream>>>(X, P, G, rn);
    pair_kernel<<<512, 512, 0, stream>>>(G, rn, T, out);
}

// Round 5
// 71.515 us; speedup vs baseline: 1.0843x; 1.0843x over previous
//
#include <hip/hip_runtime.h>
#include <hip/hip_bf16.h>
#include <math.h>

#define N_ 256
#define C_ 100
#define D_ 512
#define LOG2E 1.44269504088896f

// ---- ws layout (float indices) ----
#define WS_GX  0         // [256][256] raw X.X gram (bf16 inputs, f32 acc)
#define WS_GTP 65536     // [25][256][4] raw X.P gram, class-quad-major (coalesced in K2)
#define WS_RN  91136     // [356] scales 3/||row|| (from bf16 gram diag, as validated R1)

typedef __attribute__((ext_vector_type(8))) short short8;
typedef __attribute__((ext_vector_type(4))) float floatx4;

__device__ inline float waveReduceSum(float v) {
    #pragma unroll
    for (int off = 32; off > 0; off >>= 1) v += __shfl_xor(v, off, 64);
    return v;
}
__device__ inline float clip1(float x) { return fminf(fmaxf(x, -1.0f), 1.0f); }

__device__ inline short8 cvt8(float4 a, float4 b) {
    union { __hip_bfloat16 h[8]; short8 s; } u;
    u.h[0] = __float2bfloat16(a.x); u.h[1] = __float2bfloat16(a.y);
    u.h[2] = __float2bfloat16(a.z); u.h[3] = __float2bfloat16(a.w);
    u.h[4] = __float2bfloat16(b.x); u.h[5] = __float2bfloat16(b.y);
    u.h[6] = __float2bfloat16(b.z); u.h[7] = __float2bfloat16(b.w);
    return u.s;
}

// K1: needed-tiles-only Gram with 4-way K-split.
// One 16x16 tile per block (256 thr): wave w computes k in [w*128, w*128+128)
// (4 MFMA chain instead of 16), LDS-combine, wave 0 stores. Tiles:
//   [0,256):   X.X  tm=t>>4, tn=t&15  -> Gx row-major (+ rn[0..255] on diag)
//   [256,368): X.P  tm=u/7,  tc=u%7   -> GTP[c>>2][row][c&3] (c<100)
//   [368,375): P.P diag               -> rn[256+pr] only
// Math per element identical to validated R1 gemm (bf16 cvt in-register,
// f32 MFMA acc); only the K-sum association differs (w0+w1+w2+w3).
__global__ __launch_bounds__(256)
void gemm_kernel(const float* __restrict__ X, const float* __restrict__ P,
                 float* __restrict__ ws) {
    float* Gx  = ws + WS_GX;
    float* GTP = ws + WS_GTP;
    float* rn  = ws + WS_RN;
    __shared__ floatx4 accl[3][64];
    int tile = blockIdx.x;
    int t = threadIdx.x, w = t >> 6, lane = t & 63;
    int r = lane & 15, quad = lane >> 4;
    const float *arow, *brow;
    int tm, tn, mode;
    if (tile < 256) {
        mode = 0; tm = tile >> 4; tn = tile & 15;
        arow = X + (size_t)(tm * 16 + r) * D_;
        brow = X + (size_t)(tn * 16 + r) * D_;
    } else if (tile < 368) {
        int u = tile - 256; mode = 1; tm = u / 7; tn = u - tm * 7;
        int pb = tn * 16 + r; if (pb >= C_) pb = 0;   // garbage lanes, not stored
        arow = X + (size_t)(tm * 16 + r) * D_;
        brow = P + (size_t)pb * D_;
    } else {
        mode = 2; tm = tile - 368; tn = tm;
        int pa = tm * 16 + r; if (pa >= C_) pa = 0;
        arow = P + (size_t)pa * D_;
        brow = arow;
    }
    floatx4 acc = {0.0f, 0.0f, 0.0f, 0.0f};
    int k0 = w * 128;
    #pragma unroll
    for (int kk = 0; kk < 128; kk += 32) {
        const float4* ap = (const float4*)(arow + k0 + kk + quad * 8);
        const float4* bp = (const float4*)(brow + k0 + kk + quad * 8);
        short8 av = cvt8(ap[0], ap[1]);
        short8 bv = cvt8(bp[0], bp[1]);
        acc = __builtin_amdgcn_mfma_f32_16x16x32_bf16(av, bv, acc, 0, 0, 0);
    }
    if (w) accl[w - 1][lane] = acc;
    __syncthreads();
    if (w == 0) {
        acc += accl[0][lane]; acc += accl[1][lane]; acc += accl[2][lane];
        if (mode == 0) {
            int row0 = tm * 16 + quad * 4, col = tn * 16 + r;
            #pragma unroll
            for (int i = 0; i < 4; ++i) Gx[(row0 + i) * 256 + col] = acc[i];
            if (tm == tn && (r >> 2) == quad)
                rn[tm * 16 + r] = 3.0f * rsqrtf(fmaxf(acc[r & 3], 1e-24f));
        } else if (mode == 1) {
            int c = tn * 16 + r;
            if (c < C_) {
                int row0 = tm * 16 + quad * 4;
                #pragma unroll
                for (int i = 0; i < 4; ++i)
                    GTP[(c >> 2) * 1024 + (row0 + i) * 4 + (c & 3)] = acc[i];
            }
        } else {
            if ((r >> 2) == quad) {
                int pr = tm * 16 + r;
                if (pr < C_) rn[256 + pr] = 3.0f * rsqrtf(fmaxf(acc[r & 3], 1e-24f));
            }
        }
    }
}

// K2: 256 blocks x 1024 thr (16 waves = 4 waves/SIMD, 1 block/CU).
// Slot = 4 lanes (m = t>>2 in [0,256), p = t&3): pair (b, m) for m>b with
// T-diff; m==b = diag = real loss (lam=1 exact reduction, validated R2-R4).
// Class loop: 7 iters of one float4 each, quad q = p+4k (q<25):
//   a2 = GTP4[q*256+m] -> COALESCED over consecutive m (vs R1's 32-line gather)
//   a1 = GTP4[q*256+b] -> 4 lines/wave, L1-hot
//   g  = Gx[b*256+m]   -> coalesced
// No LDS staging of G (L2-resident; R4 proved staging is overhead).
// Whole-wave ballot skip for m-ranges entirely below the diagonal.
__global__ __launch_bounds__(1024)
void pair_kernel(const float* __restrict__ ws, const int* __restrict__ T,
                 float* __restrict__ out) {
    const float* Gx  = ws + WS_GX;
    const float4* G4 = (const float4*)(ws + WS_GTP);   // [25*256] float4
    const float* rn  = ws + WS_RN;
    __shared__ int Tl[256];
    __shared__ int hist[C_];
    __shared__ float sxl[256];
    __shared__ float red[16];

    int t = threadIdx.x, w = t >> 6, lane = t & 63;
    int b = blockIdx.x;
    if (t < 256) { Tl[t] = T[t]; sxl[t] = rn[t]; }
    if (t < C_) hist[t] = 0;
    __syncthreads();
    if (t < 256) atomicAdd(&hist[Tl[t]], 1);

    int m = t >> 2, p = t & 3;
    int t1 = Tl[b];
    float s1 = sxl[b];
    bool diag = (m == b);
    bool act = diag || ((m > b) && (Tl[m] != t1));
    float contrib = 0.0f;
    if (__ballot(act)) {
        if (act) {
            int t2 = Tl[m];
            float sc2 = sxl[m];
            float sp1 = rn[256 + t1], sp2 = rn[256 + t2];
            const float* GTPf = (const float*)G4;
            float ip11 = GTPf[(t1 >> 2) * 1024 + b * 4 + (t1 & 3)] * s1 * sp1;
            float ip12 = GTPf[(t2 >> 2) * 1024 + b * 4 + (t2 & 3)] * s1 * sp2;
            float ip21 = GTPf[(t1 >> 2) * 1024 + m * 4 + (t1 & 3)] * sc2 * sp1;
            float ip22 = GTPf[(t2 >> 2) * 1024 + m * 4 + (t2 & 3)] * sc2 * sp2;
            float X1P1 = clip1(ip11), X1P2 = clip1(ip12);
            float X2P1 = clip1(ip21), X2P2 = clip1(ip22);
            float num = X2P2 - X2P1;
            float den = num + X1P1 - X1P2;
            float lam = fminf(fmaxf(num / den, 0.3f), 0.7f);
            if (diag) lam = 1.0f;        // exact real-loss reduction
            float oml = 1.0f - lam;
            float g = Gx[b * 256 + m] * s1 * sc2;   // irrelevant when lam=1
            float wn2 = 9.0f * (lam * lam + oml * oml) + 2.0f * lam * oml * g;
            float ss2 = 6.0f * rsqrtf(fmaxf(wn2, 1e-24f));
            float la = ss2 * lam * s1 * LOG2E, lb = ss2 * oml * sc2 * LOG2E;
            float sm = 0.0f;
            #pragma unroll
            for (int k = 0; k < 7; ++k) {
                int q = p + 4 * k;
                if (q < 25) {
                    float4 a1 = G4[q * 256 + b];
                    float4 a2 = G4[q * 256 + m];
                    const float4 s4 = *(const float4*)(rn + 256 + q * 4);
                    sm += exp2f(s4.x * (la * a1.x + lb * a2.x));
                    sm += exp2f(s4.y * (la * a1.y + lb * a2.y));
                    sm += exp2f(s4.z * (la * a1.z + lb * a2.z));
                    sm += exp2f(s4.w * (la * a1.w + lb * a2.w));
                }
            }
            sm += __shfl_xor(sm, 1, 64);   // act is slot-uniform -> partners valid
            sm += __shfl_xor(sm, 2, 64);
            if (p == 0) {
                float LSE = logf(sm);
                float ec1 = ss2 * (lam * ip11 + oml * ip21);
                float ec2 = ss2 * (lam * ip12 + oml * ip22);
                contrib = LSE - lam * ec1 - oml * ec2;
            }
        }
    }
    float rsum = waveReduceSum(contrib);
    if (lane == 0) red[w] = rsum;
    __syncthreads();                      // red + hist atomics complete
    if (w == 0) {
        float same;
        { float n = (float)hist[lane]; same = 0.5f * n * (n - 1.0f); }
        if (lane + 64 < C_) { float n = (float)hist[lane + 64]; same += 0.5f * n * (n - 1.0f); }
        float bs = (lane < 16) ? red[lane] : 0.0f;
        same = waveReduceSum(same);
        bs = waveReduceSum(bs);
        if (lane == 0) atomicAdd(out, bs / (32896.0f - same));
    }
}

extern "C" void kernel_launch(void* const* d_in, const int* in_sizes, int n_in,
                              void* d_out, int out_size, void* d_ws, size_t ws_size,
                              hipStream_t stream) {
    const float* X = (const float*)d_in[0];   // (256, 512) f32
    const float* P = (const float*)d_in[1];   // (100, 512) f32
    const int*   T = (const int*)d_in[2];     // (256,) i32
    // d_in[3] = indices, unused
    float* ws = (float*)d_ws;                 // ~366 KB used
    float* out = (float*)d_out;

    gemm_kernel<<<375, 256, 0, stream>>>(X, P, ws);
    pair_kernel<<<N_, 1024, 0, stream>>>(ws, T, out);
}

// Round 6
// 68.864 us; speedup vs baseline: 1.1260x; 1.0385x over previous
//
#include <hip/hip_runtime.h>
#include <hip/hip_bf16.h>
#include <math.h>

#define N_ 256
#define C_ 100
#define D_ 512
#define LOG2E 1.44269504088896f

// ---- ws layout (float indices) ----
#define WS_GX  0         // [256][256] raw X.X gram; ONLY upper triangle (m>=b) valid
#define WS_GTP 65536     // [25][256][4] raw X.P gram, class-quad-major (coalesced in K2)
#define WS_RN  91136     // [356] scales 3/||row|| (bf16-gram diag, validated R1-R5)

typedef __attribute__((ext_vector_type(8))) short short8;
typedef __attribute__((ext_vector_type(4))) float floatx4;

__device__ inline float waveReduceSum(float v) {
    #pragma unroll
    for (int off = 32; off > 0; off >>= 1) v += __shfl_xor(v, off, 64);
    return v;
}
__device__ inline float clip1(float x) { return fminf(fmaxf(x, -1.0f), 1.0f); }

__device__ inline short8 cvt8(float4 a, float4 b) {
    union { __hip_bfloat16 h[8]; short8 s; } u;
    u.h[0] = __float2bfloat16(a.x); u.h[1] = __float2bfloat16(a.y);
    u.h[2] = __float2bfloat16(a.z); u.h[3] = __float2bfloat16(a.w);
    u.h[4] = __float2bfloat16(b.x); u.h[5] = __float2bfloat16(b.y);
    u.h[6] = __float2bfloat16(b.z); u.h[7] = __float2bfloat16(b.w);
    return u.s;
}

// K1: needed-tiles-only Gram, 4-way K-split (validated R5 body). Tile set cut
// 375 -> 255 by symmetry: K2 reads Gx[b][m] only for m>=b, so only the
// upper-triangle X.X tiles (tm<=tn, 136) are computed; lower tri stays poison
// (never consumed). Tiles:
//   [0,136):   upper X.X (tm<=tn)  -> Gx row-major (+ rn[0..255] on diag tiles)
//   [136,248): X.P  tm=u/7 tn=u%7  -> GTP[c>>2][row][c&3]
//   [248,255): P.P diag            -> rn[256+pr]
__global__ __launch_bounds__(256)
void gemm_kernel(const float* __restrict__ X, const float* __restrict__ P,
                 float* __restrict__ ws) {
    float* Gx  = ws + WS_GX;
    float* GTP = ws + WS_GTP;
    float* rn  = ws + WS_RN;
    __shared__ floatx4 accl[3][64];
    int tile = blockIdx.x;
    int t = threadIdx.x, w = t >> 6, lane = t & 63;
    int r = lane & 15, quad = lane >> 4;
    const float *arow, *brow;
    int tm, tn, mode;
    if (tile < 136) {                        // upper-tri X.X
        mode = 0;
        int u = tile; tm = 0;
        while (u >= 16 - tm) { u -= 16 - tm; ++tm; }   // uniform scalar decode
        tn = tm + u;
        arow = X + (size_t)(tm * 16 + r) * D_;
        brow = X + (size_t)(tn * 16 + r) * D_;
    } else if (tile < 248) {                 // X.P
        int u = tile - 136; mode = 1; tm = u / 7; tn = u - tm * 7;
        int pb = tn * 16 + r; if (pb >= C_) pb = 0;    // garbage lanes, not stored
        arow = X + (size_t)(tm * 16 + r) * D_;
        brow = P + (size_t)pb * D_;
    } else {                                 // P.P diag (norms only)
        mode = 2; tm = tile - 248; tn = tm;
        int pa = tm * 16 + r; if (pa >= C_) pa = 0;
        arow = P + (size_t)pa * D_;
        brow = arow;
    }
    floatx4 acc = {0.0f, 0.0f, 0.0f, 0.0f};
    int k0 = w * 128;
    #pragma unroll
    for (int kk = 0; kk < 128; kk += 32) {
        const float4* ap = (const float4*)(arow + k0 + kk + quad * 8);
        const float4* bp = (const float4*)(brow + k0 + kk + quad * 8);
        short8 av = cvt8(ap[0], ap[1]);
        short8 bv = cvt8(bp[0], bp[1]);
        acc = __builtin_amdgcn_mfma_f32_16x16x32_bf16(av, bv, acc, 0, 0, 0);
    }
    if (w) accl[w - 1][lane] = acc;
    __syncthreads();
    if (w == 0) {
        acc += accl[0][lane]; acc += accl[1][lane]; acc += accl[2][lane];
        if (mode == 0) {
            int row0 = tm * 16 + quad * 4, col = tn * 16 + r;
            #pragma unroll
            for (int i = 0; i < 4; ++i) Gx[(row0 + i) * 256 + col] = acc[i];
            if (tm == tn && (r >> 2) == quad)
                rn[tm * 16 + r] = 3.0f * rsqrtf(fmaxf(acc[r & 3], 1e-24f));
        } else if (mode == 1) {
            int c = tn * 16 + r;
            if (c < C_) {
                int row0 = tm * 16 + quad * 4;
                #pragma unroll
                for (int i = 0; i < 4; ++i)
                    GTP[(c >> 2) * 1024 + (row0 + i) * 4 + (c & 3)] = acc[i];
            }
        } else {
            if ((r >> 2) == quad) {
                int pr = tm * 16 + r;
                if (pr < C_) rn[256 + pr] = 3.0f * rsqrtf(fmaxf(acc[r & 3], 1e-24f));
            }
        }
    }
}

// K2: 256 blocks x 1024 thr; slot = 4 lanes (m = t>>2, p = t&3): pair (b,m)
// for m>b with T-diff; m==b = diag = real loss (lam=1 exact reduction,
// validated R2-R5). BARRIER-FREE front end:
//  - all independent loads (T[b], T[m], rn[b], rn[m], Gx[b][m], 7x a2 float4)
//    issue at kernel entry straight from global (L3-resident);
//  - each WAVE stages GTP row b + sps into its private LDS buffer (written
//    and read by the same wave -> ordered by lgkmcnt, no __syncthreads);
//    this also supplies ip11/ip12/sp1/sp2 without a second global trip;
//  - only ip21/ip22 (t1/t2-dependent row-m gathers) are a dependent trip;
//  - the two barriers sit at the tail (hist + epilogue only).
// Math identical to R5 (absmax 0.0).
__global__ __launch_bounds__(1024)
void pair_kernel(const float* __restrict__ ws, const int* __restrict__ T,
                 float* __restrict__ out) {
    const float* Gx   = ws + WS_GX;
    const float4* G4  = (const float4*)(ws + WS_GTP);
    const float* GTPf = ws + WS_GTP;
    const float* rn   = ws + WS_RN;
    __shared__ __attribute__((aligned(16))) float wbufA[16][104];
    __shared__ __attribute__((aligned(16))) float wbufS[16][104];
    __shared__ int hist[C_];
    __shared__ float red[16];

    int t = threadIdx.x, w = t >> 6, lane = t & 63;
    int b = blockIdx.x;
    int m = t >> 2, p = t & 3;

    // ---- early independent loads (no barrier ahead of the math) ----
    int t1 = T[b];                         // uniform
    int t2 = T[m];                         // per-slot
    float s1 = rn[b], sc2 = rn[m];
    float graw = 0.0f;
    if (m >= b) graw = Gx[b * 256 + m];    // lower tri = poison, never loaded
    float4 a2r[7];
    #pragma unroll
    for (int k = 0; k < 7; ++k) {
        int q = p + 4 * k;
        a2r[k] = (float4){0.f, 0.f, 0.f, 0.f};
        if (q < 25 && m >= b) a2r[k] = G4[q * 256 + m];
    }
    int Tt = (t < 256) ? T[t] : 0;         // hist feed
    if (t < C_) hist[t] = 0;
    // per-wave staging of GTP row b + sps (same-wave write->read, no barrier)
    if (lane < 25) {
        float4 av = G4[lane * 256 + b];
        float4 sv = *(const float4*)(rn + 256 + lane * 4);
        *(float4*)&wbufA[w][lane * 4] = av;
        *(float4*)&wbufS[w][lane * 4] = sv;
    }

    // ---- pair math ----
    bool diag = (m == b);
    bool act = diag || ((m > b) && (t2 != t1));
    float contrib = 0.0f;
    if (act) {
        float ip11r = wbufA[w][t1], ip12r = wbufA[w][t2];
        float sp1 = wbufS[w][t1], sp2 = wbufS[w][t2];
        float ip21r = GTPf[(t1 >> 2) * 1024 + m * 4 + (t1 & 3)];
        float ip22r = GTPf[(t2 >> 2) * 1024 + m * 4 + (t2 & 3)];
        float ip11 = ip11r * s1 * sp1, ip12 = ip12r * s1 * sp2;
        float ip21 = ip21r * sc2 * sp1, ip22 = ip22r * sc2 * sp2;
        float X1P1 = clip1(ip11), X1P2 = clip1(ip12);
        float X2P1 = clip1(ip21), X2P2 = clip1(ip22);
        float num = X2P2 - X2P1;
        float den = num + X1P1 - X1P2;
        float lam = fminf(fmaxf(num / den, 0.3f), 0.7f);
        if (diag) lam = 1.0f;              // exact real-loss reduction
        float oml = 1.0f - lam;
        float g = graw * s1 * sc2;
        float wn2 = 9.0f * (lam * lam + oml * oml) + 2.0f * lam * oml * g;
        float ss2 = 6.0f * rsqrtf(fmaxf(wn2, 1e-24f));
        float la = ss2 * lam * s1 * LOG2E, lb = ss2 * oml * sc2 * LOG2E;
        float sm = 0.0f;
        #pragma unroll
        for (int k = 0; k < 7; ++k) {
            int q = p + 4 * k;
            if (q < 25) {
                float4 a1 = *(const float4*)&wbufA[w][q * 4];
                float4 s4 = *(const float4*)&wbufS[w][q * 4];
                float4 a2 = a2r[k];
                sm += exp2f(s4.x * (la * a1.x + lb * a2.x));
                sm += exp2f(s4.y * (la * a1.y + lb * a2.y));
                sm += exp2f(s4.z * (la * a1.z + lb * a2.z));
                sm += exp2f(s4.w * (la * a1.w + lb * a2.w));
            }
        }
        sm += __shfl_xor(sm, 1, 64);       // act is slot-uniform -> partners valid
        sm += __shfl_xor(sm, 2, 64);
        if (p == 0) {
            float LSE = logf(sm);
            float ec1 = ss2 * (lam * ip11 + oml * ip21);
            float ec2 = ss2 * (lam * ip12 + oml * ip22);
            contrib = LSE - lam * ec1 - oml * ec2;
        }
    }
    float rsum = waveReduceSum(contrib);
    if (lane == 0) red[w] = rsum;
    __syncthreads();                       // bar1: hist zero + red complete
    if (t < 256) atomicAdd(&hist[Tt], 1);
    __syncthreads();                       // bar2: hist complete
    if (w == 0) {
        float same;
        { float n = (float)hist[lane]; same = 0.5f * n * (n - 1.0f); }
        if (lane + 64 < C_) { float n = (float)hist[lane + 64]; same += 0.5f * n * (n - 1.0f); }
        float bs = (lane < 16) ? red[lane] : 0.0f;
        same = waveReduceSum(same);
        bs = waveReduceSum(bs);
        if (lane == 0) atomicAdd(out, bs / (32896.0f - same));
    }
}

extern "C" void kernel_launch(void* const* d_in, const int* in_sizes, int n_in,
                              void* d_out, int out_size, void* d_ws, size_t ws_size,
                              hipStream_t stream) {
    const float* X = (const float*)d_in[0];   // (256, 512) f32
    const float* P = (const float*)d_in[1];   // (100, 512) f32
    const int*   T = (const int*)d_in[2];     // (256,) i32
    // d_in[3] = indices, unused
    float* ws = (float*)d_ws;                 // ~366 KB used
    float* out = (float*)d_out;

    gemm_kernel<<<255, 256, 0, stream>>>(X, P, ws);
    pair_kernel<<<N_, 1024, 0, stream>>>(ws, T, out);
}